// Round 1
// baseline (1297.514 us; speedup 1.0000x reference)
//
#include <hip/hip_runtime.h>

// Problem constants (from reference): B=256, T=512, I=64, H=512.
#define BATCH    256
#define TSTEPS   512
#define IDIM     64
#define HDIM     512
#define KEXT     576          // H + I  (concatenated [h ; x_t] dot)
#define NTHREADS 512          // one thread per output column j
#define REG_PAIRS  224        // k in [0,448) held in VGPRs as half2 pairs
#define REG_CHUNKS 56         // 4 pairs (8 halfs) per 16B chunk
#define LDS_CHUNKS 16         // chunks 56..71 -> k in [448,576) held in LDS
#define LDSW_STRIDE 17        // uint4 per row: 16 chunks + 1 pad (bank spread)

// LDS layout (dynamic shared):
//   ldsW : 512 rows * 17 uint4 = 139264 B
//   hbuf : 2 buffers * 640 _Float16 = 2560 B   (576 used: [0,512)=h, [512,576)=x_t)
//   red  : 8 floats (wave partials) = 32 B
#define LDSW_BYTES (512 * LDSW_STRIDE * 16)
#define HBUF_OFF   LDSW_BYTES
#define HBUF_ELEMS 640
#define RED_OFF    (HBUF_OFF + 2 * HBUF_ELEMS * 2)
#define SMEM_BYTES (RED_OFF + 64)

typedef _Float16 half2_t __attribute__((ext_vector_type(2)));
typedef _Float16 half8_t __attribute__((ext_vector_type(8)));

union H8U {
    half8_t v;
    half2_t p[4];
    uint4   u4;
};

__device__ __forceinline__ float fdot2(half2_t a, half2_t b, float c) {
#if __has_builtin(__builtin_amdgcn_fdot2)
    return __builtin_amdgcn_fdot2(a, b, c, false);
#else
    return c + (float)a[0] * (float)b[0] + (float)a[1] * (float)b[1];
#endif
}

// tanh(x) = 1 - 2/(exp(2x)+1), exp(2x)=exp2(x*2/ln2). HW exp2+rcp, ~1e-6 abs err.
__device__ __forceinline__ float fast_tanh(float x) {
    float e = __builtin_amdgcn_exp2f(x * 2.88539008177792681472f);
    return 1.0f - 2.0f * __builtin_amdgcn_rcpf(e + 1.0f);
}

__global__ __launch_bounds__(NTHREADS, 2)
void rnn_persist(const float* __restrict__ x,    // (B,T,I)
                 const float* __restrict__ Wxh,  // (I,H)
                 const float* __restrict__ Whh,  // (H,H)
                 const float* __restrict__ bias, // (H)
                 const float* __restrict__ fcw,  // (1,H)
                 const float* __restrict__ fcb,  // (1)
                 float* __restrict__ out)        // (B,1)
{
    extern __shared__ char smem[];
    uint4*     ldsW = reinterpret_cast<uint4*>(smem);
    _Float16*  hbuf = reinterpret_cast<_Float16*>(smem + HBUF_OFF);
    float*     red  = reinterpret_cast<float*>(smem + RED_OFF);

    const int j = threadIdx.x;      // output column
    const int b = blockIdx.x;       // batch row

    // ---- Prologue: load this column's weights ----
    // Registers: k in [0,448), packed as (k, k+1) fp16 pairs.
    half2_t wreg[REG_PAIRS];
#pragma unroll
    for (int p = 0; p < REG_PAIRS; ++p) {
        const int k = 2 * p;
        half2_t w;
        w[0] = (_Float16)Whh[(size_t)k * HDIM + j];
        w[1] = (_Float16)Whh[(size_t)(k + 1) * HDIM + j];
        wreg[p] = w;
    }
    // LDS: k in [448,576). cc<8 -> W_hh tail, cc>=8 -> W_xh.
#pragma unroll
    for (int cc = 0; cc < LDS_CHUNKS; ++cc) {
        H8U u;
#pragma unroll
        for (int q = 0; q < 4; ++q) {
            const int k0 = 448 + 8 * cc + 2 * q;
            const int k1 = k0 + 1;
            half2_t w;
            w[0] = (_Float16)(k0 < HDIM ? Whh[(size_t)k0 * HDIM + j]
                                        : Wxh[(size_t)(k0 - HDIM) * HDIM + j]);
            w[1] = (_Float16)(k1 < HDIM ? Whh[(size_t)k1 * HDIM + j]
                                        : Wxh[(size_t)(k1 - HDIM) * HDIM + j]);
            u.p[q] = w;
        }
        ldsW[j * LDSW_STRIDE + cc] = u.u4;
    }

    const float bj   = bias[j];
    const float fcwj = fcw[j];

    // ---- Init step-0 staging: h = 0, x_0 appended ----
    hbuf[j] = (_Float16)0.0f;
    if (j < IDIM) hbuf[HDIM + j] = (_Float16)x[((size_t)b * TSTEPS + 0) * IDIM + j];
    __syncthreads();

    // ---- Recurrent loop ----
    float hval = 0.0f;
    for (int t = 0; t < TSTEPS; ++t) {
        const int cur = t & 1;
        const int nxt = cur ^ 1;
        const _Float16* hb = hbuf + cur * HBUF_ELEMS;

        // Prefetch next x_t early (wave 0 only; latency hidden behind dots).
        float xv = 0.0f;
        const bool do_x = (j < IDIM) && (t + 1 < TSTEPS);
        if (do_x) xv = x[((size_t)b * TSTEPS + (t + 1)) * IDIM + j];

        float a0 = bj, a1 = 0.0f, a2 = 0.0f, a3 = 0.0f;
#pragma unroll
        for (int c = 0; c < REG_CHUNKS; ++c) {
            H8U u;
            u.v = *reinterpret_cast<const half8_t*>(hb + 8 * c);  // wave-uniform (broadcast)
            a0 = fdot2(u.p[0], wreg[4 * c + 0], a0);
            a1 = fdot2(u.p[1], wreg[4 * c + 1], a1);
            a2 = fdot2(u.p[2], wreg[4 * c + 2], a2);
            a3 = fdot2(u.p[3], wreg[4 * c + 3], a3);
        }
#pragma unroll
        for (int cc = 0; cc < LDS_CHUNKS; ++cc) {
            H8U u, w;
            u.v  = *reinterpret_cast<const half8_t*>(hb + 8 * (REG_CHUNKS + cc));
            w.u4 = ldsW[j * LDSW_STRIDE + cc];
            a0 = fdot2(u.p[0], w.p[0], a0);
            a1 = fdot2(u.p[1], w.p[1], a1);
            a2 = fdot2(u.p[2], w.p[2], a2);
            a3 = fdot2(u.p[3], w.p[3], a3);
        }
        const float a = (a0 + a1) + (a2 + a3);
        hval = fast_tanh(a);

        hbuf[nxt * HBUF_ELEMS + j] = (_Float16)hval;          // publish h_{t+1} input
        if (do_x) hbuf[nxt * HBUF_ELEMS + HDIM + j] = (_Float16)xv;
        __syncthreads();  // hbuf[nxt] complete before next step reads it
    }

    // ---- Epilogue: out[b] = sum_j h_T[j]*fc_w[j] + fc_b ----
    float partial = hval * fcwj;
#pragma unroll
    for (int off = 32; off >= 1; off >>= 1)
        partial += __shfl_down(partial, off, 64);
    if ((j & 63) == 0) red[j >> 6] = partial;
    __syncthreads();
    if (j == 0) {
        float s = 0.0f;
#pragma unroll
        for (int w = 0; w < 8; ++w) s += red[w];
        out[b] = s + fcb[0];
    }
}

extern "C" void kernel_launch(void* const* d_in, const int* in_sizes, int n_in,
                              void* d_out, int out_size, void* d_ws, size_t ws_size,
                              hipStream_t stream) {
    const float* x    = (const float*)d_in[0];
    const float* Wxh  = (const float*)d_in[1];
    const float* Whh  = (const float*)d_in[2];
    const float* bias = (const float*)d_in[3];
    const float* fcw  = (const float*)d_in[4];
    const float* fcb  = (const float*)d_in[5];
    float* out = (float*)d_out;

    // Opt in to >64KB dynamic LDS (idempotent, capture-safe host call).
    hipFuncSetAttribute(reinterpret_cast<const void*>(rnn_persist),
                        hipFuncAttributeMaxDynamicSharedMemorySize, SMEM_BYTES);

    rnn_persist<<<BATCH, NTHREADS, SMEM_BYTES, stream>>>(x, Wxh, Whh, bias, fcw, fcb, out);
}

// Round 2
// 1152.359 us; speedup vs baseline: 1.1260x; 1.1260x over previous
//
#include <hip/hip_runtime.h>

// Problem: B=256, T=512, I=64, H=512.  h_t = tanh(x_t@Wxh + b + h@Whh); out = h_T@fc_w.T + fc_b
// Mapping: 1 batch row per block per CU (256 blocks), 512 threads = 1 thread per h-column.
// Whh column j lives per-thread: 208 half2 pairs in VGPRs (k<416) + 12 LDS b128 chunks (k 416..512).
// xh precomputed by a separate GEMM pass into d_ws (fp16, 134 MB) when ws_size allows;
// otherwise fused K=576 fallback.

#define BATCH    256
#define TSTEPS   512
#define IDIM     64
#define HDIM     512
#define NTH      512

typedef _Float16 half2_t __attribute__((ext_vector_type(2)));
typedef _Float16 half8_t __attribute__((ext_vector_type(8)));

union H8U {
    half8_t v;
    half2_t p[4];
    uint4   u4;
};

__device__ __forceinline__ float fdot2(half2_t a, half2_t b, float c) {
#if __has_builtin(__builtin_amdgcn_fdot2)
    return __builtin_amdgcn_fdot2(a, b, c, false);
#else
    return c + (float)a[0] * (float)b[0] + (float)a[1] * (float)b[1];
#endif
}

__device__ __forceinline__ float fast_tanh(float x) {
    float e = __builtin_amdgcn_exp2f(x * 2.88539008177792681472f);
    return 1.0f - 2.0f * __builtin_amdgcn_rcpf(e + 1.0f);
}

// ============================= xh precompute =============================
// xh[bt][j] = sum_i x[bt][i]*Wxh[i][j] + b[j], fp16.  One block: 16 rows x 512 cols.
#define XH_ROWS 16
__global__ __launch_bounds__(NTH, 4)
void xh_gemm(const float* __restrict__ x, const float* __restrict__ Wxh,
             const float* __restrict__ bias, _Float16* __restrict__ xh)
{
    const int j = threadIdx.x;
    const size_t r0 = (size_t)blockIdx.x * XH_ROWS;
    float wcol[IDIM];
#pragma unroll
    for (int i = 0; i < IDIM; ++i) wcol[i] = Wxh[(size_t)i * HDIM + j];
    const float bj = bias[j];
#pragma unroll
    for (int r = 0; r < XH_ROWS; ++r) {
        const float* xr = x + (r0 + r) * IDIM;   // wave-uniform address -> s_loads
        float acc = bj;
#pragma unroll
        for (int i = 0; i < IDIM; ++i) acc += xr[i] * wcol[i];
        xh[(r0 + r) * HDIM + j] = (_Float16)acc;
    }
}

// ============================= split-path RNN (K=512) =============================
#define S_RP   208          // reg pairs: k in [0,416)
#define S_RC   52           // 16B chunks from registers
#define S_LC   12           // LDS chunks: k in [416,512)
#define S_LSTR 13           // uint4 per row (12 + 1 pad)
#define S_LDSW_BYTES (512 * S_LSTR * 16)          // 106496
#define S_HBUF_OFF   S_LDSW_BYTES
#define S_HBUF_ELEMS 512
#define S_RED_OFF    (S_HBUF_OFF + 2 * S_HBUF_ELEMS * 2)
#define S_SMEM_BYTES (S_RED_OFF + 64)             // ~108.7 KB -> 1 block/CU

__global__ __attribute__((amdgpu_flat_work_group_size(NTH, NTH), amdgpu_waves_per_eu(2, 2)))
void rnn_split(const _Float16* __restrict__ xh,  // (B*T, H) fp16, bias folded in
               const float* __restrict__ Whh,    // (H,H)
               const float* __restrict__ fcw,    // (1,H)
               const float* __restrict__ fcb,    // (1)
               float* __restrict__ out)          // (B,1)
{
    extern __shared__ char smem[];
    uint4*    ldsW = reinterpret_cast<uint4*>(smem);
    _Float16* hbuf = reinterpret_cast<_Float16*>(smem + S_HBUF_OFF);
    float*    red  = reinterpret_cast<float*>(smem + S_RED_OFF);

    const int j = threadIdx.x;
    const int b = blockIdx.x;

    // ---- Prologue: column j of Whh ----
    half2_t wreg[S_RP];
#pragma unroll
    for (int p = 0; p < S_RP; ++p) {
        const int k = 2 * p;
        half2_t w;
        w[0] = (_Float16)Whh[(size_t)k * HDIM + j];
        w[1] = (_Float16)Whh[(size_t)(k + 1) * HDIM + j];
        wreg[p] = w;
    }
#pragma unroll
    for (int cc = 0; cc < S_LC; ++cc) {
        H8U u;
#pragma unroll
        for (int q = 0; q < 4; ++q) {
            const int k0 = 416 + 8 * cc + 2 * q;
            half2_t w;
            w[0] = (_Float16)Whh[(size_t)k0 * HDIM + j];
            w[1] = (_Float16)Whh[(size_t)(k0 + 1) * HDIM + j];
            u.p[q] = w;
        }
        ldsW[j * S_LSTR + cc] = u.u4;
    }

    const float fcwj = fcw[j];
    const _Float16* xhb = xh + (size_t)b * TSTEPS * HDIM;

    hbuf[j] = (_Float16)0.0f;       // h_0 = 0 (buffer 0)
    __syncthreads();

    float hval = 0.0f;
    for (int t = 0; t < TSTEPS; ++t) {
        const int cur = t & 1;
        const int nxt = cur ^ 1;
        const _Float16* hb = hbuf + cur * S_HBUF_ELEMS;

        // Issue this step's xh load early; consumed after the dot loop.
        const float xv = (float)xhb[(size_t)t * HDIM + j];

        float a0 = 0.0f, a1 = 0.0f, a2 = 0.0f, a3 = 0.0f;
#pragma unroll
        for (int c = 0; c < S_RC; ++c) {
            H8U u;
            u.v = *reinterpret_cast<const half8_t*>(hb + 8 * c);   // uniform -> broadcast
            a0 = fdot2(u.p[0], wreg[4 * c + 0], a0);
            a1 = fdot2(u.p[1], wreg[4 * c + 1], a1);
            a2 = fdot2(u.p[2], wreg[4 * c + 2], a2);
            a3 = fdot2(u.p[3], wreg[4 * c + 3], a3);
        }
#pragma unroll
        for (int cc = 0; cc < S_LC; ++cc) {
            H8U u, w;
            u.v  = *reinterpret_cast<const half8_t*>(hb + 8 * (S_RC + cc));
            w.u4 = ldsW[j * S_LSTR + cc];
            a0 = fdot2(u.p[0], w.p[0], a0);
            a1 = fdot2(u.p[1], w.p[1], a1);
            a2 = fdot2(u.p[2], w.p[2], a2);
            a3 = fdot2(u.p[3], w.p[3], a3);
        }
        hval = fast_tanh(((a0 + a1) + (a2 + a3)) + xv);

        hbuf[nxt * S_HBUF_ELEMS + j] = (_Float16)hval;
        __syncthreads();
    }

    // ---- Epilogue ----
    float partial = hval * fcwj;
#pragma unroll
    for (int off = 32; off >= 1; off >>= 1)
        partial += __shfl_down(partial, off, 64);
    if ((j & 63) == 0) red[j >> 6] = partial;
    __syncthreads();
    if (j == 0) {
        float s = 0.0f;
#pragma unroll
        for (int w = 0; w < 8; ++w) s += red[w];
        out[b] = s + fcb[0];
    }
}

// ============================= fused fallback (K=576) =============================
#define F_RP   216          // reg pairs: k in [0,432)
#define F_RC   54
#define F_LC   18           // LDS chunks: k in [432,576)
#define F_LSTR 19
#define F_LDSW_BYTES (512 * F_LSTR * 16)          // 155648
#define F_HBUF_OFF   F_LDSW_BYTES
#define F_HBUF_ELEMS 640                          // [0,512)=h, [512,576)=x_t
#define F_RED_OFF    (F_HBUF_OFF + 2 * F_HBUF_ELEMS * 2)
#define F_SMEM_BYTES (F_RED_OFF + 64)             // ~158.2 KB

__global__ __attribute__((amdgpu_flat_work_group_size(NTH, NTH), amdgpu_waves_per_eu(2, 2)))
void rnn_fused(const float* __restrict__ x, const float* __restrict__ Wxh,
               const float* __restrict__ Whh, const float* __restrict__ bias,
               const float* __restrict__ fcw, const float* __restrict__ fcb,
               float* __restrict__ out)
{
    extern __shared__ char smem[];
    uint4*    ldsW = reinterpret_cast<uint4*>(smem);
    _Float16* hbuf = reinterpret_cast<_Float16*>(smem + F_HBUF_OFF);
    float*    red  = reinterpret_cast<float*>(smem + F_RED_OFF);

    const int j = threadIdx.x;
    const int b = blockIdx.x;

    half2_t wreg[F_RP];
#pragma unroll
    for (int p = 0; p < F_RP; ++p) {
        const int k = 2 * p;
        half2_t w;
        w[0] = (_Float16)Whh[(size_t)k * HDIM + j];
        w[1] = (_Float16)Whh[(size_t)(k + 1) * HDIM + j];
        wreg[p] = w;
    }
#pragma unroll
    for (int cc = 0; cc < F_LC; ++cc) {
        H8U u;
#pragma unroll
        for (int q = 0; q < 4; ++q) {
            const int k0 = 432 + 8 * cc + 2 * q;
            const int k1 = k0 + 1;
            half2_t w;
            w[0] = (_Float16)(k0 < HDIM ? Whh[(size_t)k0 * HDIM + j]
                                        : Wxh[(size_t)(k0 - HDIM) * HDIM + j]);
            w[1] = (_Float16)(k1 < HDIM ? Whh[(size_t)k1 * HDIM + j]
                                        : Wxh[(size_t)(k1 - HDIM) * HDIM + j]);
            u.p[q] = w;
        }
        ldsW[j * F_LSTR + cc] = u.u4;
    }

    const float bj   = bias[j];
    const float fcwj = fcw[j];

    hbuf[j] = (_Float16)0.0f;
    if (j < IDIM) hbuf[HDIM + j] = (_Float16)x[((size_t)b * TSTEPS + 0) * IDIM + j];
    __syncthreads();

    float hval = 0.0f;
    for (int t = 0; t < TSTEPS; ++t) {
        const int cur = t & 1;
        const int nxt = cur ^ 1;
        const _Float16* hb = hbuf + cur * F_HBUF_ELEMS;

        float xv = 0.0f;
        const bool do_x = (j < IDIM) && (t + 1 < TSTEPS);
        if (do_x) xv = x[((size_t)b * TSTEPS + (t + 1)) * IDIM + j];

        float a0 = bj, a1 = 0.0f, a2 = 0.0f, a3 = 0.0f;
#pragma unroll
        for (int c = 0; c < F_RC; ++c) {
            H8U u;
            u.v = *reinterpret_cast<const half8_t*>(hb + 8 * c);
            a0 = fdot2(u.p[0], wreg[4 * c + 0], a0);
            a1 = fdot2(u.p[1], wreg[4 * c + 1], a1);
            a2 = fdot2(u.p[2], wreg[4 * c + 2], a2);
            a3 = fdot2(u.p[3], wreg[4 * c + 3], a3);
        }
#pragma unroll
        for (int cc = 0; cc < F_LC; ++cc) {
            H8U u, w;
            u.v  = *reinterpret_cast<const half8_t*>(hb + 8 * (F_RC + cc));
            w.u4 = ldsW[j * F_LSTR + cc];
            a0 = fdot2(u.p[0], w.p[0], a0);
            a1 = fdot2(u.p[1], w.p[1], a1);
            a2 = fdot2(u.p[2], w.p[2], a2);
            a3 = fdot2(u.p[3], w.p[3], a3);
        }
        hval = fast_tanh((a0 + a1) + (a2 + a3));

        hbuf[nxt * F_HBUF_ELEMS + j] = (_Float16)hval;
        if (do_x) hbuf[nxt * F_HBUF_ELEMS + HDIM + j] = (_Float16)xv;
        __syncthreads();
    }

    float partial = hval * fcwj;
#pragma unroll
    for (int off = 32; off >= 1; off >>= 1)
        partial += __shfl_down(partial, off, 64);
    if ((j & 63) == 0) red[j >> 6] = partial;
    __syncthreads();
    if (j == 0) {
        float s = 0.0f;
#pragma unroll
        for (int w = 0; w < 8; ++w) s += red[w];
        out[b] = s + fcb[0];
    }
}

// ============================= host =============================
extern "C" void kernel_launch(void* const* d_in, const int* in_sizes, int n_in,
                              void* d_out, int out_size, void* d_ws, size_t ws_size,
                              hipStream_t stream) {
    const float* x    = (const float*)d_in[0];
    const float* Wxh  = (const float*)d_in[1];
    const float* Whh  = (const float*)d_in[2];
    const float* bias = (const float*)d_in[3];
    const float* fcw  = (const float*)d_in[4];
    const float* fcb  = (const float*)d_in[5];
    float* out = (float*)d_out;

    const size_t xh_bytes = (size_t)BATCH * TSTEPS * HDIM * sizeof(_Float16);  // 134 MB
    if (ws_size >= xh_bytes) {
        hipFuncSetAttribute(reinterpret_cast<const void*>(rnn_split),
                            hipFuncAttributeMaxDynamicSharedMemorySize, S_SMEM_BYTES);
        _Float16* xh = (_Float16*)d_ws;
        xh_gemm<<<(BATCH * TSTEPS) / XH_ROWS, NTH, 0, stream>>>(x, Wxh, bias, xh);
        rnn_split<<<BATCH, NTH, S_SMEM_BYTES, stream>>>(xh, Whh, fcw, fcb, out);
    } else {
        hipFuncSetAttribute(reinterpret_cast<const void*>(rnn_fused),
                            hipFuncAttributeMaxDynamicSharedMemorySize, F_SMEM_BYTES);
        rnn_fused<<<BATCH, NTH, F_SMEM_BYTES, stream>>>(x, Wxh, Whh, bias, fcw, fcb, out);
    }
}